// Round 5
// baseline (1715.011 us; speedup 1.0000x reference)
//
#include <hip/hip_runtime.h>
#include <hip/hip_bf16.h>

#define NPTS 200000
#define CIN 64
#define KOFF 27
#define MTILE 128
#define MAXPAIR (MTILE * KOFF)   // 3456
#define MAXFRAG (MAXPAIR / 16)   // 216

typedef __attribute__((ext_vector_type(8))) short bf16x8;
typedef __attribute__((ext_vector_type(4))) float f32x4;

__device__ inline void gload16(const void* g, void* lds) {
  __builtin_amdgcn_global_load_lds(
      (const __attribute__((address_space(1))) void*)g,
      (__attribute__((address_space(3))) void*)lds, 16, 0, 0);
}

__device__ inline ushort f2bf(float f) {
  union { float f; unsigned u; } x; x.f = f;
  unsigned r = (x.u + 0x7fffu + ((x.u >> 16) & 1u)) >> 16;
  return (ushort)r;
}

// feats fp32 -> bf16
__global__ void cvt_bf16_kernel(const float* __restrict__ in,
                                ushort* __restrict__ out, int n4) {
  int stride = gridDim.x * blockDim.x;
  for (int i = blockIdx.x * blockDim.x + threadIdx.x; i < n4; i += stride) {
    float4 v = ((const float4*)in)[i];
    ushort4 o;
    o.x = f2bf(v.x); o.y = f2bf(v.y); o.z = f2bf(v.z); o.w = f2bf(v.w);
    ((ushort4*)out)[i] = o;
  }
}

// W[k][c][co] fp32 -> lane-ordered bf16: Wt[k][n][kk][lane][e]
// so kernel B-load is 16B/lane fully coalesced (lane = lhi*16+llo).
template <int Co>
__global__ void cvt_wt_kernel(const float* __restrict__ W,
                              ushort* __restrict__ Wt) {
  constexpr int NF = Co / 16;
  int total = KOFF * CIN * Co;
  for (int i = blockIdx.x * blockDim.x + threadIdx.x; i < total;
       i += gridDim.x * blockDim.x) {
    int k = i / (CIN * Co);
    int rem = i - k * (CIN * Co);
    int c = rem / Co;
    int co = rem - c * Co;
    int n = co >> 4, llo = co & 15;
    int kk = c >> 5, lhi = (c >> 3) & 3, e = c & 7;
    int dest = (((k * NF + n) * 2 + kk) * 64 + lhi * 16 + llo) * 8 + e;
    Wt[dest] = f2bf(W[i]);
  }
}

// Sparse layer, block-local compaction:
//  - histogram/scan/scatter nbr -> k-sorted padded pair list (16-row frags)
//  - waves process frags independently (NO barriers in main loop),
//    depth-2 global_load_lds pipeline with counted vmcnt
//  - MFMA 16x16x32 per frag, scatter-add into LDS fp32 accumulator
template <int COUT, bool RELU, bool OUTBF16, int MINW>
__global__ __launch_bounds__(256, MINW)
void layer_kernel(const ushort* __restrict__ inB,
                  const ushort* __restrict__ Wt,
                  const float* __restrict__ bias,
                  const int* __restrict__ nbr,
                  void* __restrict__ outp,
                  const ushort* __restrict__ zpage) {
  constexpr int NF = COUT / 16;
  constexpr int STRIDE = COUT + 4;          // de-conflict scatter banks
  __shared__ float acc[MTILE * STRIDE];     // 34.8KB / 67.6KB
  __shared__ int pairs[MAXPAIR];            // 13.8KB
  __shared__ int frag_k[MAXFRAG];           // 0.9KB
  __shared__ int cnt[KOFF], offs[KOFF], cur[KOFF];
  __shared__ int nfrag_s, npad_s;
  __shared__ ushort A_buf[4][2][16 * CIN];  // 4 waves x dbuf x 2KB = 16KB

  const int tid = threadIdx.x;
  const int j0 = blockIdx.x * MTILE;
  const int w = tid >> 6, l = tid & 63;
  const int llo = l & 15, lhi = l >> 4;

  // ---- init ----
  for (int i = tid; i < MTILE * STRIDE; i += 256) acc[i] = 0.f;
  if (tid < KOFF) cnt[tid] = 0;
  __syncthreads();

  // ---- pass 1: per-k histogram of valid neighbors ----
  for (int idx = tid; idx < MTILE * KOFF; idx += 256) {
    int row = idx / KOFF;
    if (j0 + row < NPTS) {
      int v = nbr[j0 * KOFF + idx];
      if (v >= 0) atomicAdd(&cnt[idx - row * KOFF], 1);
    }
  }
  __syncthreads();

  // ---- scan + fragment table (thread 0, 27 iters) ----
  if (tid == 0) {
    int pos = 0, nf = 0;
    for (int k = 0; k < KOFF; ++k) {
      offs[k] = pos; cur[k] = pos;
      int nfk = (cnt[k] + 15) >> 4;
      for (int f = 0; f < nfk; ++f) frag_k[nf++] = k;
      pos += nfk << 4;
    }
    nfrag_s = nf; npad_s = pos;
  }
  __syncthreads();
  const int npad = npad_s;
  for (int i = tid; i < npad; i += 256) pairs[i] = -1;  // sentinels
  __syncthreads();

  // ---- pass 2: scatter pairs (pack src*128 + local_row) ----
  for (int idx = tid; idx < MTILE * KOFF; idx += 256) {
    int row = idx / KOFF;
    if (j0 + row < NPTS) {
      int v = nbr[j0 * KOFF + idx];
      if (v >= 0) {
        int k = idx - row * KOFF;
        int p = atomicAdd(&cur[k], 1);
        pairs[p] = v * MTILE + row;
      }
    }
  }
  __syncthreads();
  const int nfrag = nfrag_s;

  // ---- main loop: wave-independent fragments, no barriers ----
  ushort* buf0 = &A_buf[w][0][0];
  ushort* buf1 = &A_buf[w][1][0];

  auto stage = [&](int f, ushort* buf) {
#pragma unroll
    for (int i = 0; i < 2; ++i) {
      int r = i * 8 + (l >> 3);
      int c = l & 7;
      int csw = c ^ (r & 7);               // source-side swizzle, LDS linear
      int pr = pairs[f * 16 + r];
      const ushort* g = (pr < 0) ? (zpage + csw * 8)
                                 : (inB + (pr >> 7) * CIN + csw * 8);
      gload16(g, buf + i * 512 + l * 8);   // wave-uniform base + lane*16B
    }
  };

  int myf = w;
  if (myf < nfrag) stage(myf, buf0);
  int bufsel = 0;
  while (myf < nfrag) {
    int nxt = myf + 4;
    if (nxt < nfrag) {
      stage(nxt, bufsel ? buf0 : buf1);
      asm volatile("s_waitcnt vmcnt(2)" ::: "memory");
    } else {
      asm volatile("s_waitcnt vmcnt(0)" ::: "memory");
    }
    __builtin_amdgcn_sched_barrier(0);

    const ushort* bufc = bufsel ? buf1 : buf0;
    bf16x8 a0 = *(const bf16x8*)&bufc[llo * CIN + ((lhi ^ (llo & 7)) * 8)];
    bf16x8 a1 = *(const bf16x8*)&bufc[llo * CIN + (((4 + lhi) ^ (llo & 7)) * 8)];

    int k = frag_k[myf];
    const ushort* Wk = Wt + k * (NF * 2 * 64 * 8);
    int4 pr4 = *(const int4*)&pairs[myf * 16 + lhi * 4];
    int r0 = pr4.x & (MTILE - 1), r1 = pr4.y & (MTILE - 1);
    int r2 = pr4.z & (MTILE - 1), r3 = pr4.w & (MTILE - 1);

#pragma unroll
    for (int n = 0; n < NF; ++n) {
      bf16x8 b0 = *(const bf16x8*)&Wk[((n * 2 + 0) * 64 + l) * 8];
      bf16x8 b1 = *(const bf16x8*)&Wk[((n * 2 + 1) * 64 + l) * 8];
      f32x4 accf = {0.f, 0.f, 0.f, 0.f};
      accf = __builtin_amdgcn_mfma_f32_16x16x32_bf16(a0, b0, accf, 0, 0, 0);
      accf = __builtin_amdgcn_mfma_f32_16x16x32_bf16(a1, b1, accf, 0, 0, 0);
      int col = n * 16 + llo;
      atomicAdd(&acc[r0 * STRIDE + col], accf[0]);
      atomicAdd(&acc[r1 * STRIDE + col], accf[1]);
      atomicAdd(&acc[r2 * STRIDE + col], accf[2]);
      atomicAdd(&acc[r3 * STRIDE + col], accf[3]);
    }
    myf = nxt; bufsel ^= 1;
  }
  __syncthreads();

  // ---- epilogue: bias (+relu) + store ----
  for (int i = tid; i < MTILE * COUT / 4; i += 256) {
    int row = i / (COUT / 4);
    int c4 = (i - row * (COUT / 4)) * 4;
    int j = j0 + row;
    if (j < NPTS) {
      float4 v = *(const float4*)&acc[row * STRIDE + c4];
      float4 bb = *(const float4*)&bias[c4];
      v.x += bb.x; v.y += bb.y; v.z += bb.z; v.w += bb.w;
      if (RELU) {
        v.x = fmaxf(v.x, 0.f); v.y = fmaxf(v.y, 0.f);
        v.z = fmaxf(v.z, 0.f); v.w = fmaxf(v.w, 0.f);
      }
      if (OUTBF16) {
        ushort4 o; o.x = f2bf(v.x); o.y = f2bf(v.y);
        o.z = f2bf(v.z); o.w = f2bf(v.w);
        *(ushort4*)&((ushort*)outp)[j * COUT + c4] = o;
      } else {
        *(float4*)&((float*)outp)[j * COUT + c4] = v;
      }
    }
  }
}

extern "C" void kernel_launch(void* const* d_in, const int* in_sizes, int n_in,
                              void* d_out, int out_size, void* d_ws, size_t ws_size,
                              hipStream_t stream) {
  const float* feats = (const float*)d_in[0];
  const float* W1 = (const float*)d_in[1];
  const float* b1 = (const float*)d_in[2];
  const float* W2 = (const float*)d_in[3];
  const float* b2 = (const float*)d_in[4];
  const float* W3 = (const float*)d_in[5];
  const float* b3 = (const float*)d_in[6];
  const int* nbr = (const int*)d_in[7];

  // d_out doubles as scratch: featsB [0,25.6MB) dead after L1;
  // h1B [76.8MB,..) dead after L2. ws: weights+zpage first, h2B after (~27.7MB).
  char* ws = (char*)d_ws;
  ushort* featsB = (ushort*)d_out;
  ushort* h1B = (ushort*)((char*)d_out + 76800000);
  ushort* W1t = (ushort*)(ws);
  ushort* W2t = (ushort*)(ws + 262144);
  ushort* W3t = (ushort*)(ws + 524288);
  ushort* zpage = (ushort*)(ws + 1048576);
  ushort* h2B = (ushort*)(ws + 2097152);

  hipMemsetAsync(zpage, 0, 256, stream);

  cvt_bf16_kernel<<<2048, 256, 0, stream>>>(feats, featsB, NPTS * CIN / 4);
  cvt_wt_kernel<64><<<256, 256, 0, stream>>>(W1, W1t);
  cvt_wt_kernel<64><<<256, 256, 0, stream>>>(W2, W2t);
  cvt_wt_kernel<128><<<512, 256, 0, stream>>>(W3, W3t);

  int grid = (NPTS + MTILE - 1) / MTILE;
  layer_kernel<64, true, true, 2><<<grid, 256, 0, stream>>>(featsB, W1t, b1, nbr, h1B, zpage);
  layer_kernel<64, true, true, 2><<<grid, 256, 0, stream>>>(h1B, W2t, b2, nbr, h2B, zpage);
  layer_kernel<128, false, false, 1><<<grid, 256, 0, stream>>>(h2B, W3t, b3, nbr, d_out, zpage);
}

// Round 7
// 655.006 us; speedup vs baseline: 2.6183x; 2.6183x over previous
//
#include <hip/hip_runtime.h>
#include <hip/hip_bf16.h>

#define NPTS 200000
#define CIN 64
#define KOFF 27
#define MTILE 128
#define MAXPAIR (MTILE * KOFF)   // 3456
#define MAXFRAG (MAXPAIR / 16)   // 216
#define GROUP 4                  // fragments staged per barrier phase

typedef __attribute__((ext_vector_type(8))) short bf16x8;
typedef __attribute__((ext_vector_type(4))) float f32x4;

__device__ inline void gload16(const void* g, void* lds) {
  __builtin_amdgcn_global_load_lds(
      (const __attribute__((address_space(1))) void*)g,
      (__attribute__((address_space(3))) void*)lds, 16, 0, 0);
}

__device__ inline ushort f2bf(float f) {
  union { float f; unsigned u; } x; x.f = f;
  unsigned r = (x.u + 0x7fffu + ((x.u >> 16) & 1u)) >> 16;
  return (ushort)r;
}

// feats fp32 -> bf16
__global__ void cvt_bf16_kernel(const float* __restrict__ in,
                                ushort* __restrict__ out, int n4) {
  int stride = gridDim.x * blockDim.x;
  for (int i = blockIdx.x * blockDim.x + threadIdx.x; i < n4; i += stride) {
    float4 v = ((const float4*)in)[i];
    ushort4 o;
    o.x = f2bf(v.x); o.y = f2bf(v.y); o.z = f2bf(v.z); o.w = f2bf(v.w);
    ((ushort4*)out)[i] = o;
  }
}

// W[k][c][co] fp32 -> lane-ordered bf16: Wt[k][n][kk][lane][e]
// (HW-verified layout from round 5: B-frag load is 16B/lane, coalesced)
template <int Co>
__global__ void cvt_wt_kernel(const float* __restrict__ W,
                              ushort* __restrict__ Wt) {
  constexpr int NF = Co / 16;
  int total = KOFF * CIN * Co;
  for (int i = blockIdx.x * blockDim.x + threadIdx.x; i < total;
       i += gridDim.x * blockDim.x) {
    int k = i / (CIN * Co);
    int rem = i - k * (CIN * Co);
    int c = rem / Co;
    int co = rem - c * Co;
    int n = co >> 4, llo = co & 15;
    int kk = c >> 5, lhi = (c >> 3) & 3, e = c & 7;
    int dest = (((k * NF + n) * 2 + kk) * 64 + lhi * 16 + llo) * 8 + e;
    Wt[dest] = f2bf(W[i]);
  }
}

// Sparse layer, block-local compaction, cooperative pipeline:
//  - pair build (histogram/scan/scatter) as round 5 (HW-verified)
//  - fragments processed in GROUPs of 4: all 256 threads stage the group
//    (global_load_lds, double-buffered), one barrier per group
//  - wave w owns columns [w*16*NSLICE ...): LDS accumulate is plain
//    read-add-write, race-free (sentinel rows -> dump row 128, adds 0.0)
template <int COUT, bool RELU, bool OUTBF16, int MINW>
__global__ __launch_bounds__(256, MINW)
void sp_layer_kernel(const ushort* __restrict__ inB,
                     const ushort* __restrict__ WtL,
                     const float* __restrict__ bias,
                     const int* __restrict__ nbr,
                     void* __restrict__ outp,
                     const ushort* __restrict__ zpage) {
  constexpr int NF = COUT / 16;
  constexpr int NSLICE = NF / 4;            // col-slices per wave: 1 or 2
  constexpr int STRIDE = COUT + 4;
  __shared__ float acc[129 * STRIDE];       // row 128 = sentinel dump
  __shared__ int pairs[MAXPAIR];
  __shared__ int frag_k[MAXFRAG];
  __shared__ int cnt[KOFF], cur[KOFF];
  __shared__ int nfrag_s, npad_s;
  __shared__ ushort A_buf[2][GROUP * 16 * CIN];  // 2 x 8KB

  const int tid = threadIdx.x;
  const int j0 = blockIdx.x * MTILE;
  const int w = tid >> 6, l = tid & 63;
  const int llo = l & 15, lhi = l >> 4;

  // ---- init ----
  for (int i = tid; i < 129 * STRIDE / 4; i += 256)
    ((float4*)acc)[i] = make_float4(0.f, 0.f, 0.f, 0.f);
  if (tid < KOFF) cnt[tid] = 0;
  __syncthreads();

  // ---- histogram of valid neighbors per k ----
  for (int idx = tid; idx < MTILE * KOFF; idx += 256) {
    int row = idx / KOFF;
    if (j0 + row < NPTS) {
      int v = nbr[j0 * KOFF + idx];
      if (v >= 0) atomicAdd(&cnt[idx - row * KOFF], 1);
    }
  }
  __syncthreads();

  // ---- scan + fragment table ----
  if (tid == 0) {
    int pos = 0, nf = 0;
    for (int k = 0; k < KOFF; ++k) {
      cur[k] = pos;
      int nfk = (cnt[k] + 15) >> 4;
      for (int f = 0; f < nfk; ++f) frag_k[nf++] = k;
      pos += nfk << 4;
    }
    nfrag_s = nf; npad_s = pos;
  }
  __syncthreads();
  const int npad = npad_s;
  for (int i = tid; i < npad; i += 256) pairs[i] = -1;
  __syncthreads();

  // ---- scatter pairs (src*128 + local_row) ----
  for (int idx = tid; idx < MTILE * KOFF; idx += 256) {
    int row = idx / KOFF;
    if (j0 + row < NPTS) {
      int v = nbr[j0 * KOFF + idx];
      if (v >= 0) {
        int k = idx - row * KOFF;
        int p = atomicAdd(&cur[k], 1);
        pairs[p] = v * MTILE + row;
      }
    }
  }
  __syncthreads();
  const int nfrag = nfrag_s;
  const int ngrp = (nfrag + GROUP - 1) / GROUP;

  // ---- cooperative group staging (all 256 threads, source-swizzled) ----
  auto stageg = [&](int g, int buf) {
#pragma unroll
    for (int r = 0; r < 2; ++r) {
      int lin = r * 256 + tid;          // 512 16B-chunks per group
      int fi = lin >> 7;
      int row = (lin >> 3) & 15;
      int c = lin & 7;
      int csw = c ^ (row & 7);
      int f = g * GROUP + fi;
      int pr = (f < nfrag) ? pairs[f * 16 + row] : -1;
      const ushort* gp = (pr < 0) ? (zpage + csw * 8)
                                  : (inB + (pr >> 7) * CIN + csw * 8);
      gload16(gp, &A_buf[buf][lin * 8]);
    }
  };

  auto computeg = [&](int g, int buf) {
#pragma unroll
    for (int fi = 0; fi < GROUP; ++fi) {
      int f = g * GROUP + fi;
      if (f >= nfrag) break;            // uniform across block
      const ushort* Ab = &A_buf[buf][fi * 16 * CIN];
      bf16x8 a0 = *(const bf16x8*)&Ab[llo * CIN + ((lhi ^ (llo & 7)) * 8)];
      bf16x8 a1 = *(const bf16x8*)&Ab[llo * CIN + (((4 + lhi) ^ (llo & 7)) * 8)];
      int k = frag_k[f];
      int4 pr4 = *(const int4*)&pairs[f * 16 + lhi * 4];
      int r0 = pr4.x < 0 ? 128 : (pr4.x & (MTILE - 1));
      int r1 = pr4.y < 0 ? 128 : (pr4.y & (MTILE - 1));
      int r2 = pr4.z < 0 ? 128 : (pr4.z & (MTILE - 1));
      int r3 = pr4.w < 0 ? 128 : (pr4.w & (MTILE - 1));
      const ushort* Wk = WtL + k * (NF * 1024);
#pragma unroll
      for (int nn = 0; nn < NSLICE; ++nn) {
        int n = w + nn * 4;             // wave-owned column slice
        bf16x8 b0 = *(const bf16x8*)&Wk[((n * 2 + 0) * 64 + l) * 8];
        bf16x8 b1 = *(const bf16x8*)&Wk[((n * 2 + 1) * 64 + l) * 8];
        f32x4 cf = {0.f, 0.f, 0.f, 0.f};
        cf = __builtin_amdgcn_mfma_f32_16x16x32_bf16(a0, b0, cf, 0, 0, 0);
        cf = __builtin_amdgcn_mfma_f32_16x16x32_bf16(a1, b1, cf, 0, 0, 0);
        int col = n * 16 + llo;
        acc[r0 * STRIDE + col] += cf[0];   // race-free: wave-unique cols,
        acc[r1 * STRIDE + col] += cf[1];   // frag rows distinct, sentinels
        acc[r2 * STRIDE + col] += cf[2];   // add exact 0.0 to dump row
        acc[r3 * STRIDE + col] += cf[3];
      }
    }
  };

  // ---- main loop: {stage g+1 | compute g | barrier} ----
  stageg(0, 0);
  __syncthreads();
  for (int g = 0; g < ngrp; ++g) {
    if (g + 1 < ngrp) stageg(g + 1, (g + 1) & 1);
    computeg(g, g & 1);
    __syncthreads();
  }

  // ---- epilogue: bias (+relu) + store ----
  for (int i = tid; i < MTILE * COUT / 4; i += 256) {
    int row = i / (COUT / 4);
    int c4 = (i - row * (COUT / 4)) * 4;
    int j = j0 + row;
    if (j < NPTS) {
      float4 v = *(const float4*)&acc[row * STRIDE + c4];
      float4 bb = *(const float4*)&bias[c4];
      v.x += bb.x; v.y += bb.y; v.z += bb.z; v.w += bb.w;
      if (RELU) {
        v.x = fmaxf(v.x, 0.f); v.y = fmaxf(v.y, 0.f);
        v.z = fmaxf(v.z, 0.f); v.w = fmaxf(v.w, 0.f);
      }
      if (OUTBF16) {
        ushort4 o; o.x = f2bf(v.x); o.y = f2bf(v.y);
        o.z = f2bf(v.z); o.w = f2bf(v.w);
        *(ushort4*)&((ushort*)outp)[j * COUT + c4] = o;
      } else {
        *(float4*)&((float*)outp)[j * COUT + c4] = v;
      }
    }
  }
}

extern "C" void kernel_launch(void* const* d_in, const int* in_sizes, int n_in,
                              void* d_out, int out_size, void* d_ws, size_t ws_size,
                              hipStream_t stream) {
  const float* feats = (const float*)d_in[0];
  const float* W1 = (const float*)d_in[1];
  const float* b1 = (const float*)d_in[2];
  const float* W2 = (const float*)d_in[3];
  const float* b2 = (const float*)d_in[4];
  const float* W3 = (const float*)d_in[5];
  const float* b3 = (const float*)d_in[6];
  const int* nbr = (const int*)d_in[7];

  // d_out as scratch (round-4 verified layout): featsB@0 dead after L1,
  // h1B@76.8MB dead after L2. ws: Wt1|Wt2|Wt3|zpage|h2B (~27.7MB).
  char* ws = (char*)d_ws;
  ushort* featsB = (ushort*)d_out;
  ushort* h1B = (ushort*)((char*)d_out + 76800000);
  ushort* W1t = (ushort*)(ws);
  ushort* W2t = (ushort*)(ws + 262144);
  ushort* W3t = (ushort*)(ws + 524288);
  ushort* zpage = (ushort*)(ws + 1048576);
  ushort* h2B = (ushort*)(ws + 2097152);

  hipMemsetAsync(zpage, 0, 256, stream);

  cvt_bf16_kernel<<<2048, 256, 0, stream>>>(feats, featsB, NPTS * CIN / 4);
  cvt_wt_kernel<64><<<256, 256, 0, stream>>>(W1, W1t);
  cvt_wt_kernel<64><<<256, 256, 0, stream>>>(W2, W2t);
  cvt_wt_kernel<128><<<512, 256, 0, stream>>>(W3, W3t);

  int grid = (NPTS + MTILE - 1) / MTILE;
  sp_layer_kernel<64, true, true, 2><<<grid, 256, 0, stream>>>(featsB, W1t, b1, nbr, h1B, zpage);
  sp_layer_kernel<64, true, true, 2><<<grid, 256, 0, stream>>>(h1B, W2t, b2, nbr, h2B, zpage);
  sp_layer_kernel<128, false, false, 1><<<grid, 256, 0, stream>>>(h2B, W3t, b3, nbr, d_out, zpage);
}

// Round 9
// 507.396 us; speedup vs baseline: 3.3800x; 1.2909x over previous
//
#include <hip/hip_runtime.h>
#include <hip/hip_bf16.h>

#define NPTS 200000
#define CIN 64
#define KOFF 27
#define MTILE 128
#define MAXPAIR 3520             // 216 frags * 16 + pad slack
#define MAXFRAG 220
#define GROUP 4                  // fragments per barrier phase
#define NBR_R 14                 // ceil(3456/256)

typedef __attribute__((ext_vector_type(8))) short bf16x8;
typedef __attribute__((ext_vector_type(4))) float f32x4;

__device__ inline void gload16(const void* g, void* lds) {
  __builtin_amdgcn_global_load_lds(
      (const __attribute__((address_space(1))) void*)g,
      (__attribute__((address_space(3))) void*)lds, 16, 0, 0);
}

__device__ inline ushort f2bf(float f) {
  union { float f; unsigned u; } x; x.f = f;
  unsigned r = (x.u + 0x7fffu + ((x.u >> 16) & 1u)) >> 16;
  return (ushort)r;
}

// feats fp32 -> bf16
__global__ void cvt_bf16_kernel(const float* __restrict__ in,
                                ushort* __restrict__ out, int n4) {
  int stride = gridDim.x * blockDim.x;
  for (int i = blockIdx.x * blockDim.x + threadIdx.x; i < n4; i += stride) {
    float4 v = ((const float4*)in)[i];
    ushort4 o;
    o.x = f2bf(v.x); o.y = f2bf(v.y); o.z = f2bf(v.z); o.w = f2bf(v.w);
    ((ushort4*)out)[i] = o;
  }
}

// W[k][c][TotCo] cols [ColBase,ColBase+Co) -> lane-ordered bf16
// Wt[k][n][kk][lane][e]  (HW-verified layout, rounds 5/7)
template <int Co, int TotCo, int ColBase>
__global__ void cvt_wt_kernel(const float* __restrict__ W,
                              ushort* __restrict__ Wt) {
  constexpr int NF = Co / 16;
  int total = KOFF * CIN * Co;
  for (int i = blockIdx.x * blockDim.x + threadIdx.x; i < total;
       i += gridDim.x * blockDim.x) {
    int k = i / (CIN * Co);
    int rem = i - k * (CIN * Co);
    int c = rem / Co;
    int col = rem - c * Co;
    int n = col >> 4, llo = col & 15;
    int kk = c >> 5, lhi = (c >> 3) & 3, e = c & 7;
    int dest = (((k * NF + n) * 2 + kk) * 64 + lhi * 16 + llo) * 8 + e;
    Wt[dest] = f2bf(W[k * CIN * TotCo + c * TotCo + ColBase + col]);
  }
}

// Sparse layer (COUT=64 fixed), block-local compaction:
//  - nbr read ONCE to regs; histogram/scan/scatter -> k-sorted padded frags
//  - fragment tables PADDED to full GROUPs (sentinels -> zero page/dump row)
//    so the frag loop fully unrolls: loads hoisted, latency overlapped
//  - 2 blocks/CU (65KB LDS); wave w owns cols [16w,16w+16): race-free RMW
template <bool RELU, bool OUTBF16>
__global__ __launch_bounds__(256, 2)
void sp_layer_kernel(const ushort* __restrict__ inB,
                     const ushort* __restrict__ WtL,
                     const float* __restrict__ bias,
                     const int* __restrict__ nbr,
                     void* __restrict__ outp,
                     const ushort* __restrict__ zpage,
                     int ostride, int obase) {
  constexpr int STRIDE = 68;                // 64 + 4 bank-shift
  __shared__ float acc[129 * STRIDE];       // row 128 = sentinel dump
  __shared__ int pairs[MAXPAIR];
  __shared__ int frag_k[MAXFRAG];
  __shared__ int cnt[KOFF], cur[KOFF];
  __shared__ int nfrag_s;
  __shared__ ushort A_buf[2][GROUP * 16 * CIN];  // 2 x 8KB

  const int tid = threadIdx.x;
  const int j0 = blockIdx.x * MTILE;
  const int w = tid >> 6, l = tid & 63;
  const int llo = l & 15, lhi = l >> 4;

  // ---- read nbr once into registers ----
  int mynbr[NBR_R];
#pragma unroll
  for (int r = 0; r < NBR_R; ++r) {
    int idx = r * 256 + tid;
    mynbr[r] = (idx < MTILE * KOFF && (j0 + idx / KOFF) < NPTS)
                   ? nbr[j0 * KOFF + idx] : -1;
  }

  // ---- init acc + counters ----
  for (int i = tid; i < 129 * STRIDE / 4; i += 256)
    ((float4*)acc)[i] = make_float4(0.f, 0.f, 0.f, 0.f);
  if (tid < KOFF) cnt[tid] = 0;
  __syncthreads();

  // ---- histogram from regs ----
#pragma unroll
  for (int r = 0; r < NBR_R; ++r) {
    if (mynbr[r] >= 0) {
      int idx = r * 256 + tid;
      int row = idx / KOFF;
      atomicAdd(&cnt[idx - row * KOFF], 1);
    }
  }
  __syncthreads();

  // ---- serial scan + frag table + GROUP padding ----
  if (tid == 0) {
    int pos = 0, nf = 0;
    for (int k = 0; k < KOFF; ++k) {
      cur[k] = pos;
      int nfk = (cnt[k] + 15) >> 4;
      for (int f = 0; f < nfk; ++f) frag_k[nf++] = k;
      pos += nfk << 4;
    }
    int ng = (nf + GROUP - 1) / GROUP;
    int nfp = ng * GROUP;
    for (int f = nf; f < nfp; ++f) frag_k[f] = 0;  // sentinel frags
    nfrag_s = nfp;
  }
  __syncthreads();
  const int nfp = nfrag_s;
  const int ngrp = nfp / GROUP;
  for (int i = tid; i < nfp * 16; i += 256) pairs[i] = -1;
  __syncthreads();

  // ---- scatter pairs from regs (src*128 + local_row) ----
#pragma unroll
  for (int r = 0; r < NBR_R; ++r) {
    if (mynbr[r] >= 0) {
      int idx = r * 256 + tid;
      int row = idx / KOFF;
      int k = idx - row * KOFF;
      int p = atomicAdd(&cur[k], 1);
      pairs[p] = mynbr[r] * MTILE + row;
    }
  }
  __syncthreads();

  // ---- cooperative group staging (source-swizzled, LDS linear) ----
  auto stageg = [&](int g, int buf) {
#pragma unroll
    for (int r = 0; r < 2; ++r) {
      int lin = r * 256 + tid;          // 512 16B-chunks per group
      int fi = lin >> 7;
      int row = (lin >> 3) & 15;
      int c = lin & 7;
      int csw = c ^ (row & 7);
      int pr = pairs[(g * GROUP + fi) * 16 + row];
      const ushort* gp = (pr < 0) ? (zpage + csw * 8)
                                  : (inB + (pr >> 7) * CIN + csw * 8);
      gload16(gp, &A_buf[buf][lin * 8]);
    }
  };

  const int col = w * 16 + llo;

  // ---- compute: 2 sub-phases of 2 frags, loads hoisted before use ----
  auto computeg = [&](int g, int buf) {
#pragma unroll
    for (int h = 0; h < 2; ++h) {
      bf16x8 a0[2], a1[2], b0[2], b1[2];
      int4 pr4[2];
#pragma unroll
      for (int s = 0; s < 2; ++s) {
        int fi = h * 2 + s;
        int f = g * GROUP + fi;
        const ushort* Ab = &A_buf[buf][fi * 16 * CIN];
        a0[s] = *(const bf16x8*)&Ab[llo * CIN + ((lhi ^ (llo & 7)) * 8)];
        a1[s] = *(const bf16x8*)&Ab[llo * CIN + (((4 + lhi) ^ (llo & 7)) * 8)];
        const ushort* Wk = WtL + frag_k[f] * 4096;   // NF*2*64*8
        b0[s] = *(const bf16x8*)&Wk[((w * 2 + 0) * 64 + l) * 8];
        b1[s] = *(const bf16x8*)&Wk[((w * 2 + 1) * 64 + l) * 8];
        pr4[s] = *(const int4*)&pairs[f * 16 + lhi * 4];
      }
#pragma unroll
      for (int s = 0; s < 2; ++s) {
        f32x4 cf = {0.f, 0.f, 0.f, 0.f};
        cf = __builtin_amdgcn_mfma_f32_16x16x32_bf16(a0[s], b0[s], cf, 0, 0, 0);
        cf = __builtin_amdgcn_mfma_f32_16x16x32_bf16(a1[s], b1[s], cf, 0, 0, 0);
        int r0 = pr4[s].x < 0 ? 128 : (pr4[s].x & (MTILE - 1));
        int r1 = pr4[s].y < 0 ? 128 : (pr4[s].y & (MTILE - 1));
        int r2 = pr4[s].z < 0 ? 128 : (pr4[s].z & (MTILE - 1));
        int r3 = pr4[s].w < 0 ? 128 : (pr4[s].w & (MTILE - 1));
        acc[r0 * STRIDE + col] += cf[0];   // race-free: wave-unique cols,
        acc[r1 * STRIDE + col] += cf[1];   // distinct rows per frag,
        acc[r2 * STRIDE + col] += cf[2];   // sentinels add 0.0 to dump row
        acc[r3 * STRIDE + col] += cf[3];
      }
    }
  };

  // ---- main loop: {stage g+1 | compute g | barrier} ----
  stageg(0, 0);
  __syncthreads();
  for (int g = 0; g < ngrp; ++g) {
    if (g + 1 < ngrp) stageg(g + 1, (g + 1) & 1);
    computeg(g, g & 1);
    __syncthreads();
  }

  // ---- epilogue ----
  for (int i = tid; i < MTILE * 16; i += 256) {
    int row = i >> 4;
    int c4 = (i & 15) * 4;
    int j = j0 + row;
    if (j < NPTS) {
      float4 v = *(const float4*)&acc[row * STRIDE + c4];
      float4 bb = *(const float4*)&bias[c4];
      v.x += bb.x; v.y += bb.y; v.z += bb.z; v.w += bb.w;
      if (RELU) {
        v.x = fmaxf(v.x, 0.f); v.y = fmaxf(v.y, 0.f);
        v.z = fmaxf(v.z, 0.f); v.w = fmaxf(v.w, 0.f);
      }
      if (OUTBF16) {
        ushort4 o; o.x = f2bf(v.x); o.y = f2bf(v.y);
        o.z = f2bf(v.z); o.w = f2bf(v.w);
        *(ushort4*)&((ushort*)outp)[j * ostride + obase + c4] = o;
      } else {
        *(float4*)&((float*)outp)[j * ostride + obase + c4] = v;
      }
    }
  }
}

extern "C" void kernel_launch(void* const* d_in, const int* in_sizes, int n_in,
                              void* d_out, int out_size, void* d_ws, size_t ws_size,
                              hipStream_t stream) {
  const float* feats = (const float*)d_in[0];
  const float* W1 = (const float*)d_in[1];
  const float* b1 = (const float*)d_in[2];
  const float* W2 = (const float*)d_in[3];
  const float* b2 = (const float*)d_in[4];
  const float* W3 = (const float*)d_in[5];
  const float* b3 = (const float*)d_in[6];
  const int* nbr = (const int*)d_in[7];

  // d_out as scratch: featsB@0 dead after L1, h1B@76.8MB dead after L2.
  // ws: W1t | W2t | W3ta | W3tb | zpage | h2B  (~27.7MB)
  char* ws = (char*)d_ws;
  ushort* featsB = (ushort*)d_out;
  ushort* h1B = (ushort*)((char*)d_out + 76800000);
  ushort* W1t  = (ushort*)(ws);
  ushort* W2t  = (ushort*)(ws + 262144);
  ushort* W3ta = (ushort*)(ws + 524288);
  ushort* W3tb = (ushort*)(ws + 786432);
  ushort* zpage = (ushort*)(ws + 1048576);
  ushort* h2B  = (ushort*)(ws + 2097152);

  hipMemsetAsync(zpage, 0, 256, stream);

  cvt_bf16_kernel<<<2048, 256, 0, stream>>>(feats, featsB, NPTS * CIN / 4);
  cvt_wt_kernel<64, 64, 0><<<256, 256, 0, stream>>>(W1, W1t);
  cvt_wt_kernel<64, 64, 0><<<256, 256, 0, stream>>>(W2, W2t);
  cvt_wt_kernel<64, 128, 0><<<256, 256, 0, stream>>>(W3, W3ta);
  cvt_wt_kernel<64, 128, 64><<<256, 256, 0, stream>>>(W3, W3tb);

  int grid = (NPTS + MTILE - 1) / MTILE;
  sp_layer_kernel<true, true><<<grid, 256, 0, stream>>>(
      featsB, W1t, b1, nbr, h1B, zpage, 64, 0);
  sp_layer_kernel<true, true><<<grid, 256, 0, stream>>>(
      h1B, W2t, b2, nbr, h2B, zpage, 64, 0);
  sp_layer_kernel<false, false><<<grid, 256, 0, stream>>>(
      h2B, W3ta, b3, nbr, d_out, zpage, 128, 0);
  sp_layer_kernel<false, false><<<grid, 256, 0, stream>>>(
      h2B, W3tb, b3 + 64, nbr, d_out, zpage, 128, 64);
}